// Round 1
// baseline (6625.461 us; speedup 1.0000x reference)
//
#include <hip/hip_runtime.h>
#include <math.h>

#define NE 50000
#define R2C 480
#define DD 200
#define TT 4
#define EE 100000
#define SLOPE 0.22916666666666666f

__device__ __forceinline__ float sigm(float x) { return 1.f / (1.f + expf(-x)); }

// ---------- setup kernels ----------

__global__ void init_h_kernel(const float* __restrict__ emb, float* __restrict__ h) {
  int n = blockIdx.x;            // one 64-lane wave per row
  int lane = threadIdx.x;
  size_t base = (size_t)n * DD;
  float v0 = emb[base + lane];
  float v1 = emb[base + 64 + lane];
  float v2 = emb[base + 128 + lane];
  float v3 = (lane < 8) ? emb[base + 192 + lane] : 0.f;
  float ss = v0 * v0 + v1 * v1 + v2 * v2 + v3 * v3;
#pragma unroll
  for (int off = 32; off; off >>= 1) ss += __shfl_down(ss, off);
  ss = __shfl(ss, 0);
  float inv = 1.f / fmaxf(sqrtf(ss), 1e-12f);
  h[base + lane] = v0 * inv;
  h[base + 64 + lane] = v1 * inv;
  h[base + 128 + lane] = v2 * inv;
  if (lane < 8) h[base + 192 + lane] = v3 * inv;
}

__global__ void copy_kernel(const float* __restrict__ a, float* __restrict__ b, int n) {
  int i = blockIdx.x * blockDim.x + threadIdx.x;
  if (i < n) b[i] = a[i];
}

__global__ void hist_kernel(const int* __restrict__ et, const int* __restrict__ dst,
                            int* __restrict__ et_hist, int* __restrict__ deg_hist) {
  int i = blockIdx.x * blockDim.x + threadIdx.x;
  if (i >= TT * EE) return;
  int t = i / EE;
  atomicAdd(&et_hist[t * R2C + et[i]], 1);
  atomicAdd(&deg_hist[(size_t)t * NE + dst[i]], 1);
}

__global__ void scan_rel_kernel(const int* __restrict__ et_hist, int* __restrict__ rowptr) {
  int t = blockIdx.x;
  int tid = threadIdx.x;  // block 512
  __shared__ int s[512];
  int v = (tid < R2C) ? 2 * et_hist[t * R2C + tid] : 0;
  s[tid] = v;
  __syncthreads();
  for (int off = 1; off < 512; off <<= 1) {
    int x = (tid >= off) ? s[tid - off] : 0;
    __syncthreads();
    s[tid] += x;
    __syncthreads();
  }
  if (tid < R2C) rowptr[t * (R2C + 1) + tid] = s[tid] - v;
  if (tid == 0) rowptr[t * (R2C + 1) + R2C] = 2 * EE;
}

__global__ void scan_dst_kernel(const int* __restrict__ deg_hist, int* __restrict__ rowptr,
                                float* __restrict__ normv) {
  int t = blockIdx.x;
  int tid = threadIdx.x;  // block 1024
  __shared__ int s[1024];
  __shared__ int carry;
  if (tid == 0) carry = 0;
  __syncthreads();
  for (int base = 0; base < NE; base += 1024) {
    int idx = base + tid;
    int v = (idx < NE) ? deg_hist[(size_t)t * NE + idx] : 0;
    s[tid] = v;
    __syncthreads();
    for (int off = 1; off < 1024; off <<= 1) {
      int x = (tid >= off) ? s[tid - off] : 0;
      __syncthreads();
      s[tid] += x;
      __syncthreads();
    }
    int excl = s[tid] - v + carry;
    if (idx < NE) {
      rowptr[t * (NE + 1) + idx] = excl;
      normv[(size_t)t * NE + idx] = 1.f / fmaxf((float)v, 1.f);
    }
    __syncthreads();
    if (tid == 1023) carry += s[1023];
    __syncthreads();
  }
  if (tid == 0) rowptr[t * (NE + 1) + NE] = EE;
}

__global__ void scatter_rel_kernel(const int* __restrict__ src, const int* __restrict__ dst,
                                   const int* __restrict__ et, const int* __restrict__ rowptr,
                                   int* __restrict__ cursor, int* __restrict__ sorted_ent) {
  int i = blockIdx.x * blockDim.x + threadIdx.x;
  if (i >= TT * EE) return;
  int t = i / EE;
  int r = et[i];
  int base = rowptr[t * (R2C + 1) + r];
  int p1 = base + atomicAdd(&cursor[t * R2C + r], 1);
  sorted_ent[(size_t)t * 2 * EE + p1] = src[i];
  int p2 = base + atomicAdd(&cursor[t * R2C + r], 1);
  sorted_ent[(size_t)t * 2 * EE + p2] = dst[i];
}

__global__ void scatter_dst_kernel(const int* __restrict__ dst, const int* __restrict__ rowptr,
                                   int* __restrict__ cursor, int* __restrict__ sorted_edge) {
  int i = blockIdx.x * blockDim.x + threadIdx.x;
  if (i >= TT * EE) return;
  int t = i / EE, e = i - t * EE;
  int d = dst[i];
  int base = rowptr[t * (NE + 1) + d];
  int p = base + atomicAdd(&cursor[(size_t)t * NE + d], 1);
  sorted_edge[(size_t)t * EE + p] = e;
}

// ---------- per-step kernels ----------

// one block (4 waves) per relation: mean of h rows over the relation's entity list
__global__ void relmean_kernel(const float* __restrict__ h, const int* __restrict__ rowptr,
                               const int* __restrict__ sorted_ent_t, float* __restrict__ xmean) {
  int r = blockIdx.x;
  int beg = rowptr[r], end = rowptr[r + 1];
  int lane = threadIdx.x & 63, w = threadIdx.x >> 6;
  float a0 = 0, a1 = 0, a2 = 0, a3 = 0;
  for (int i = beg + w; i < end; i += 4) {
    int idx = sorted_ent_t[i];
    const float* row = h + (size_t)idx * DD;
    a0 += row[lane];
    a1 += row[64 + lane];
    a2 += row[128 + lane];
    if (lane < 8) a3 += row[192 + lane];
  }
  __shared__ float part[4][DD];
  part[w][lane] = a0;
  part[w][64 + lane] = a1;
  part[w][128 + lane] = a2;
  if (lane < 8) part[w][192 + lane] = a3;
  __syncthreads();
  float cnt = fmaxf((float)(end - beg), 1.f);
  for (int d = threadIdx.x; d < DD; d += 256) {
    float s = part[0][d] + part[1][d] + part[2][d] + part[3][d];
    xmean[(size_t)r * DD + d] = s / cnt;
  }
}

// one block per relation: gi/gh dots + GRU gates + l2norm, h0 updated in place
__global__ void gru_kernel(const float* __restrict__ emb_rel, const float* __restrict__ xmean,
                           const float* __restrict__ W_ih, const float* __restrict__ W_hh,
                           const float* __restrict__ b_ih, const float* __restrict__ b_hh,
                           float* __restrict__ h0) {
  int r = blockIdx.x;
  int tid = threadIdx.x;
  int lane = tid & 63, w = tid >> 6;
  __shared__ float xs[2 * DD];
  __shared__ float hs[DD];
  __shared__ float gi[3 * DD];
  __shared__ float gh[3 * DD];
  __shared__ float outv[DD];
  __shared__ float red[4];
  for (int i = tid; i < DD; i += 256) {
    xs[i] = emb_rel[(size_t)r * DD + i];
    xs[DD + i] = xmean[(size_t)r * DD + i];
    hs[i] = h0[(size_t)r * DD + i];
  }
  __syncthreads();
  for (int j = w; j < 3 * DD; j += 4) {
    float p = 0;
    const float* wr = W_ih + (size_t)j * (2 * DD);
    for (int k = lane; k < 2 * DD; k += 64) p += xs[k] * wr[k];
#pragma unroll
    for (int off = 32; off; off >>= 1) p += __shfl_down(p, off);
    if (lane == 0) gi[j] = p + b_ih[j];
  }
  for (int j = w; j < 3 * DD; j += 4) {
    float p = 0;
    const float* wr = W_hh + (size_t)j * DD;
    for (int k = lane; k < DD; k += 64) p += hs[k] * wr[k];
#pragma unroll
    for (int off = 32; off; off >>= 1) p += __shfl_down(p, off);
    if (lane == 0) gh[j] = p + b_hh[j];
  }
  __syncthreads();
  if (tid < DD) {
    float rr = sigm(gi[tid] + gh[tid]);
    float z = sigm(gi[DD + tid] + gh[DD + tid]);
    float n = tanhf(gi[2 * DD + tid] + rr * gh[2 * DD + tid]);
    outv[tid] = (1.f - z) * n + z * hs[tid];
  }
  __syncthreads();
  float ss = (tid < DD) ? outv[tid] * outv[tid] : 0.f;
#pragma unroll
  for (int off = 32; off; off >>= 1) ss += __shfl_down(ss, off);
  if (lane == 0) red[w] = ss;
  __syncthreads();
  float tot = red[0] + red[1] + red[2] + red[3];
  float inv = 1.f / fmaxf(sqrtf(tot), 1e-12f);
  if (tid < DD) h0[(size_t)r * DD + tid] = outv[tid] * inv;
}

// wave per node: agg[n] = norm[n] * sum_{e->n} (hh[src]+h0[et])
__global__ void agg_kernel(const float* __restrict__ hh, const float* __restrict__ h0,
                           const int* __restrict__ rowptr, const int* __restrict__ sorted_edge_t,
                           const int* __restrict__ src_t, const int* __restrict__ et_t,
                           const float* __restrict__ normv_t, float* __restrict__ agg) {
  int w = threadIdx.x >> 6, lane = threadIdx.x & 63;
  int n = blockIdx.x * 4 + w;
  if (n >= NE) return;
  int beg = rowptr[n], end = rowptr[n + 1];
  float a0 = 0, a1 = 0, a2 = 0, a3 = 0;
  for (int i = beg; i < end; i++) {
    int e = sorted_edge_t[i];
    const float* hr = hh + (size_t)src_t[e] * DD;
    const float* qr = h0 + (size_t)et_t[e] * DD;
    a0 += hr[lane] + qr[lane];
    a1 += hr[64 + lane] + qr[64 + lane];
    a2 += hr[128 + lane] + qr[128 + lane];
    if (lane < 8) a3 += hr[192 + lane] + qr[192 + lane];
  }
  float nm = normv_t[n];
  float* out = agg + (size_t)n * DD;
  out[lane] = a0 * nm;
  out[64 + lane] = a1 * nm;
  out[128 + lane] = a2 * nm;
  if (lane < 8) out[192 + lane] = a3 * nm;
}

// C = act(A1@W1 [+ A2@W2]); tile 64 rows x 200 cols; per-thread 8x7 register block
template <int DUAL, int RRELU>
__global__ __launch_bounds__(256) void gemm_kernel(const float* __restrict__ A1,
                                                   const float* __restrict__ W1,
                                                   const float* __restrict__ A2,
                                                   const float* __restrict__ W2,
                                                   float* __restrict__ C) {
  const int KB = 8;
  __shared__ float As[KB][64];
  __shared__ float Ws[KB][DD];
  int tid = threadIdx.x;
  int tx = tid & 31, ty = tid >> 5;
  int row0 = blockIdx.x * 64;
  float acc[8][7];
#pragma unroll
  for (int i = 0; i < 8; i++)
#pragma unroll
    for (int j = 0; j < 7; j++) acc[i][j] = 0.f;

  for (int pass = 0; pass < (DUAL ? 2 : 1); ++pass) {
    const float* A = pass ? A2 : A1;
    const float* W = pass ? W2 : W1;
    for (int k0 = 0; k0 < DD; k0 += KB) {
      __syncthreads();
      {  // stage A: 64 rows x 8 k
        int r = tid >> 2;
        int kk = (tid & 3) * 2;
        int row = row0 + r;
        float v0 = 0.f, v1 = 0.f;
        if (row < NE) {
          v0 = A[(size_t)row * DD + k0 + kk];
          v1 = A[(size_t)row * DD + k0 + kk + 1];
        }
        As[kk][r] = v0;
        As[kk + 1][r] = v1;
      }
      for (int i = tid; i < KB * DD; i += 256) {  // stage W: 8 k x 200 j
        int kk = i / DD, j = i - kk * DD;
        Ws[kk][j] = W[(size_t)(k0 + kk) * DD + j];
      }
      __syncthreads();
#pragma unroll
      for (int kk = 0; kk < KB; ++kk) {
        float a[8];
#pragma unroll
        for (int rr = 0; rr < 8; rr++) a[rr] = As[kk][ty + 8 * rr];
        float b[7];
#pragma unroll
        for (int c = 0; c < 7; c++) {
          int j = tx + 32 * c;
          b[c] = (j < DD) ? Ws[kk][j] : 0.f;
        }
#pragma unroll
        for (int rr = 0; rr < 8; rr++)
#pragma unroll
          for (int c = 0; c < 7; c++) acc[rr][c] += a[rr] * b[c];
      }
    }
  }
#pragma unroll
  for (int rr = 0; rr < 8; rr++) {
    int row = row0 + ty + 8 * rr;
    if (row >= NE) continue;
#pragma unroll
    for (int c = 0; c < 7; c++) {
      int j = tx + 32 * c;
      if (j < DD) {
        float v = acc[rr][c];
        if (RRELU) v = (v >= 0.f) ? v : v * SLOPE;
        C[(size_t)row * DD + j] = v;
      }
    }
  }
}

// wave per node: cur=l2norm(hh); tw=sigmoid(tg+b); h=tw*cur+(1-tw)*h; write hist slice
__global__ void finalize_kernel(const float* __restrict__ hh, const float* __restrict__ tg,
                                const float* __restrict__ tgb, float* __restrict__ h,
                                float* __restrict__ outs) {
  int w = threadIdx.x >> 6, lane = threadIdx.x & 63;
  int n = blockIdx.x * 4 + w;
  if (n >= NE) return;
  size_t base = (size_t)n * DD;
  float c0 = hh[base + lane], c1 = hh[base + 64 + lane], c2 = hh[base + 128 + lane];
  float c3 = (lane < 8) ? hh[base + 192 + lane] : 0.f;
  float ss = c0 * c0 + c1 * c1 + c2 * c2 + c3 * c3;
#pragma unroll
  for (int off = 32; off; off >>= 1) ss += __shfl_down(ss, off);
  ss = __shfl(ss, 0);
  float inv = 1.f / fmaxf(sqrtf(ss), 1e-12f);
  float cv[4] = {c0 * inv, c1 * inv, c2 * inv, c3 * inv};
#pragma unroll
  for (int ch = 0; ch < 4; ch++) {
    int d = ch * 64 + lane;
    if (d < DD) {
      float hv = h[base + d];
      float tw = sigm(tg[base + d] + tgb[d]);
      float nv = tw * cv[ch] + (1.f - tw) * hv;
      h[base + d] = nv;
      outs[base + d] = nv;
    }
  }
}

// ---------- launch ----------

extern "C" void kernel_launch(void* const* d_in, const int* in_sizes, int n_in, void* d_out,
                              int out_size, void* d_ws, size_t ws_size, hipStream_t stream) {
  const int* src = (const int*)d_in[0];
  const int* dst = (const int*)d_in[1];
  const int* et = (const int*)d_in[2];
  const float* dyn = (const float*)d_in[3];
  const float* emb_rel = (const float*)d_in[4];
  const float* W_ih = (const float*)d_in[5];
  const float* W_hh = (const float*)d_in[6];
  const float* b_ih = (const float*)d_in[7];
  const float* b_hh = (const float*)d_in[8];
  const float* W_nb = (const float*)d_in[9];
  const float* W_lp = (const float*)d_in[10];
  const float* Wtg = (const float*)d_in[11];
  const float* tgb = (const float*)d_in[12];
  float* out = (float*)d_out;

  char* p = (char*)d_ws;
  float* h = (float*)p;        p += (size_t)NE * DD * 4;
  float* bufB = (float*)p;     p += (size_t)NE * DD * 4;
  float* agg = (float*)p;      p += (size_t)NE * DD * 4;   // also reused for time-gate output
  float* h0 = (float*)p;       p += (size_t)R2C * DD * 4;
  float* xmean = (float*)p;    p += (size_t)R2C * DD * 4;
  float* normv = (float*)p;    p += (size_t)TT * NE * 4;
  int* et_rowptr = (int*)p;    p += (size_t)TT * (R2C + 1) * 4;
  int* et_cursor = (int*)p;    p += (size_t)TT * R2C * 4;
  int* et_hist = (int*)p;      p += (size_t)TT * R2C * 4;
  int* sorted_ent = (int*)p;   p += (size_t)TT * 2 * EE * 4;
  int* dst_rowptr = (int*)p;   p += (size_t)TT * (NE + 1) * 4;
  int* dst_cursor = (int*)p;   p += (size_t)TT * NE * 4;
  int* deg_hist = (int*)p;     p += (size_t)TT * NE * 4;
  int* sorted_edge = (int*)p;  p += (size_t)TT * EE * 4;

  hipMemsetAsync(et_hist, 0, (size_t)TT * R2C * 4, stream);
  hipMemsetAsync(deg_hist, 0, (size_t)TT * NE * 4, stream);
  hipMemsetAsync(et_cursor, 0, (size_t)TT * R2C * 4, stream);
  hipMemsetAsync(dst_cursor, 0, (size_t)TT * NE * 4, stream);

  init_h_kernel<<<NE, 64, 0, stream>>>(dyn, h);
  copy_kernel<<<(R2C * DD + 255) / 256, 256, 0, stream>>>(emb_rel, h0, R2C * DD);
  hist_kernel<<<(TT * EE + 255) / 256, 256, 0, stream>>>(et, dst, et_hist, deg_hist);
  scan_rel_kernel<<<TT, 512, 0, stream>>>(et_hist, et_rowptr);
  scan_dst_kernel<<<TT, 1024, 0, stream>>>(deg_hist, dst_rowptr, normv);
  scatter_rel_kernel<<<(TT * EE + 255) / 256, 256, 0, stream>>>(src, dst, et, et_rowptr, et_cursor,
                                                                sorted_ent);
  scatter_dst_kernel<<<(TT * EE + 255) / 256, 256, 0, stream>>>(dst, dst_rowptr, dst_cursor,
                                                                sorted_edge);

  const int gemm_grid = (NE + 63) / 64;
  for (int t = 0; t < TT; t++) {
    const int* src_t = src + (size_t)t * EE;
    const int* et_t = et + (size_t)t * EE;
    float* bufA = out + (size_t)t * NE * DD;  // hist slice doubles as layer-0 scratch

    relmean_kernel<<<R2C, 256, 0, stream>>>(h, et_rowptr + t * (R2C + 1),
                                            sorted_ent + (size_t)t * 2 * EE, xmean);
    gru_kernel<<<R2C, 256, 0, stream>>>(emb_rel, xmean, W_ih, W_hh, b_ih, b_hh, h0);
    // layer 0
    agg_kernel<<<(NE + 3) / 4, 256, 0, stream>>>(h, h0, dst_rowptr + t * (NE + 1),
                                                 sorted_edge + (size_t)t * EE, src_t, et_t,
                                                 normv + (size_t)t * NE, agg);
    gemm_kernel<1, 1><<<gemm_grid, 256, 0, stream>>>(agg, W_nb, h, W_lp, bufA);
    // layer 1
    agg_kernel<<<(NE + 3) / 4, 256, 0, stream>>>(bufA, h0, dst_rowptr + t * (NE + 1),
                                                 sorted_edge + (size_t)t * EE, src_t, et_t,
                                                 normv + (size_t)t * NE, agg);
    gemm_kernel<1, 1><<<gemm_grid, 256, 0, stream>>>(agg, W_nb + DD * DD, bufA, W_lp + DD * DD,
                                                     bufB);
    // time gate: tg = h @ Wtg  (reuse agg buffer)
    gemm_kernel<0, 0><<<gemm_grid, 256, 0, stream>>>(h, Wtg, nullptr, nullptr, agg);
    finalize_kernel<<<(NE + 3) / 4, 256, 0, stream>>>(bufB, agg, tgb, h, bufA);
  }
}

// Round 2
// 4964.411 us; speedup vs baseline: 1.3346x; 1.3346x over previous
//
#include <hip/hip_runtime.h>
#include <math.h>

#define NE 50000
#define R2C 480
#define DD 200
#define TT 4
#define EE 100000
#define SLOPE 0.22916666666666666f

__device__ __forceinline__ float sigm(float x) { return 1.f / (1.f + expf(-x)); }

// ---------- setup kernels ----------

__global__ void init_h_kernel(const float* __restrict__ emb, float* __restrict__ h) {
  int n = blockIdx.x;            // one 64-lane wave per row
  int lane = threadIdx.x;
  size_t base = (size_t)n * DD;
  float v0 = emb[base + lane];
  float v1 = emb[base + 64 + lane];
  float v2 = emb[base + 128 + lane];
  float v3 = (lane < 8) ? emb[base + 192 + lane] : 0.f;
  float ss = v0 * v0 + v1 * v1 + v2 * v2 + v3 * v3;
#pragma unroll
  for (int off = 32; off; off >>= 1) ss += __shfl_down(ss, off);
  ss = __shfl(ss, 0);
  float inv = 1.f / fmaxf(sqrtf(ss), 1e-12f);
  h[base + lane] = v0 * inv;
  h[base + 64 + lane] = v1 * inv;
  h[base + 128 + lane] = v2 * inv;
  if (lane < 8) h[base + 192 + lane] = v3 * inv;
}

__global__ void copy_kernel(const float* __restrict__ a, float* __restrict__ b, int n) {
  int i = blockIdx.x * blockDim.x + threadIdx.x;
  if (i < n) b[i] = a[i];
}

// X[r][0:200] = emb_rel[r]  (X row stride 400)
__global__ void fill_x_kernel(const float* __restrict__ emb_rel, float* __restrict__ X) {
  int i = blockIdx.x * blockDim.x + threadIdx.x;
  if (i >= R2C * DD) return;
  int r = i / DD, d = i - r * DD;
  X[(size_t)r * 400 + d] = emb_rel[i];
}

__global__ void hist_kernel(const int* __restrict__ et, const int* __restrict__ dst,
                            int* __restrict__ et_hist, int* __restrict__ deg_hist) {
  int i = blockIdx.x * blockDim.x + threadIdx.x;
  if (i >= TT * EE) return;
  int t = i / EE;
  atomicAdd(&et_hist[t * R2C + et[i]], 1);
  atomicAdd(&deg_hist[(size_t)t * NE + dst[i]], 1);
}

__global__ void scan_rel_kernel(const int* __restrict__ et_hist, int* __restrict__ rowptr) {
  int t = blockIdx.x;
  int tid = threadIdx.x;  // block 512
  __shared__ int s[512];
  int v = (tid < R2C) ? 2 * et_hist[t * R2C + tid] : 0;
  s[tid] = v;
  __syncthreads();
  for (int off = 1; off < 512; off <<= 1) {
    int x = (tid >= off) ? s[tid - off] : 0;
    __syncthreads();
    s[tid] += x;
    __syncthreads();
  }
  if (tid < R2C) rowptr[t * (R2C + 1) + tid] = s[tid] - v;
  if (tid == 0) rowptr[t * (R2C + 1) + R2C] = 2 * EE;
}

__global__ void scan_dst_kernel(const int* __restrict__ deg_hist, int* __restrict__ rowptr,
                                float* __restrict__ normv) {
  int t = blockIdx.x;
  int tid = threadIdx.x;  // block 1024
  __shared__ int s[1024];
  __shared__ int carry;
  if (tid == 0) carry = 0;
  __syncthreads();
  for (int base = 0; base < NE; base += 1024) {
    int idx = base + tid;
    int v = (idx < NE) ? deg_hist[(size_t)t * NE + idx] : 0;
    s[tid] = v;
    __syncthreads();
    for (int off = 1; off < 1024; off <<= 1) {
      int x = (tid >= off) ? s[tid - off] : 0;
      __syncthreads();
      s[tid] += x;
      __syncthreads();
    }
    int excl = s[tid] - v + carry;
    if (idx < NE) {
      rowptr[t * (NE + 1) + idx] = excl;
      normv[(size_t)t * NE + idx] = 1.f / fmaxf((float)v, 1.f);
    }
    __syncthreads();
    if (tid == 1023) carry += s[1023];
    __syncthreads();
  }
  if (tid == 0) rowptr[t * (NE + 1) + NE] = EE;
}

__global__ void scatter_rel_kernel(const int* __restrict__ src, const int* __restrict__ dst,
                                   const int* __restrict__ et, const int* __restrict__ rowptr,
                                   int* __restrict__ cursor, int* __restrict__ sorted_ent) {
  int i = blockIdx.x * blockDim.x + threadIdx.x;
  if (i >= TT * EE) return;
  int t = i / EE;
  int r = et[i];
  int base = rowptr[t * (R2C + 1) + r];
  int p1 = base + atomicAdd(&cursor[t * R2C + r], 1);
  sorted_ent[(size_t)t * 2 * EE + p1] = src[i];
  int p2 = base + atomicAdd(&cursor[t * R2C + r], 1);
  sorted_ent[(size_t)t * 2 * EE + p2] = dst[i];
}

__global__ void scatter_dst_kernel(const int* __restrict__ dst, const int* __restrict__ rowptr,
                                   int* __restrict__ cursor, int* __restrict__ sorted_edge) {
  int i = blockIdx.x * blockDim.x + threadIdx.x;
  if (i >= TT * EE) return;
  int t = i / EE, e = i - t * EE;
  int d = dst[i];
  int base = rowptr[t * (NE + 1) + d];
  int p = base + atomicAdd(&cursor[(size_t)t * NE + d], 1);
  sorted_edge[(size_t)t * EE + p] = e;
}

// ---------- per-step kernels ----------

// one block (4 waves) per relation: mean of h rows; writes X[r][200:400] (row stride 400)
__global__ void relmean_kernel(const float* __restrict__ h, const int* __restrict__ rowptr,
                               const int* __restrict__ sorted_ent_t, float* __restrict__ X) {
  int r = blockIdx.x;
  int beg = rowptr[r], end = rowptr[r + 1];
  int lane = threadIdx.x & 63, w = threadIdx.x >> 6;
  float a0 = 0, a1 = 0, a2 = 0, a3 = 0;
  for (int i = beg + w; i < end; i += 4) {
    int idx = sorted_ent_t[i];
    const float* row = h + (size_t)idx * DD;
    a0 += row[lane];
    a1 += row[64 + lane];
    a2 += row[128 + lane];
    if (lane < 8) a3 += row[192 + lane];
  }
  __shared__ float part[4][DD];
  part[w][lane] = a0;
  part[w][64 + lane] = a1;
  part[w][128 + lane] = a2;
  if (lane < 8) part[w][192 + lane] = a3;
  __syncthreads();
  float cnt = fmaxf((float)(end - beg), 1.f);
  for (int d = threadIdx.x; d < DD; d += 256) {
    float s = part[0][d] + part[1][d] + part[2][d] + part[3][d];
    X[(size_t)r * 400 + 200 + d] = s / cnt;
  }
}

// C[M,N] = A[M,K] @ B[N,K]^T  (B row-major [N,K]); tile 32x32, K-chunk 16, 2x2/thread
__global__ __launch_bounds__(256) void gemm_small_bt(const float* __restrict__ A,
                                                     const float* __restrict__ B,
                                                     float* __restrict__ C, int M, int N, int K) {
  __shared__ float As[16][33];
  __shared__ float Bs[16][33];
  int tid = threadIdx.x;
  int col0 = blockIdx.x * 32;
  int row0 = blockIdx.y * 32;
  int tr = tid >> 4, tc = tid & 15;
  float a00 = 0, a01 = 0, a10 = 0, a11 = 0;
  for (int k0 = 0; k0 < K; k0 += 16) {
    __syncthreads();
    for (int i = tid; i < 512; i += 256) {
      int kk = i & 15, r = i >> 4;
      int row = row0 + r, k = k0 + kk;
      As[kk][r] = (row < M && k < K) ? A[(size_t)row * K + k] : 0.f;
    }
    for (int i = tid; i < 512; i += 256) {
      int kk = i & 15, c = i >> 4;
      int col = col0 + c, k = k0 + kk;
      Bs[kk][c] = (col < N && k < K) ? B[(size_t)col * K + k] : 0.f;
    }
    __syncthreads();
#pragma unroll
    for (int kk = 0; kk < 16; kk++) {
      float x0 = As[kk][tr * 2], x1 = As[kk][tr * 2 + 1];
      float y0 = Bs[kk][tc * 2], y1 = Bs[kk][tc * 2 + 1];
      a00 += x0 * y0;
      a01 += x0 * y1;
      a10 += x1 * y0;
      a11 += x1 * y1;
    }
  }
  int row = row0 + tr * 2, col = col0 + tc * 2;
  if (row < M && col < N) C[(size_t)row * N + col] = a00;
  if (row < M && col + 1 < N) C[(size_t)row * N + col + 1] = a01;
  if (row + 1 < M && col < N) C[(size_t)(row + 1) * N + col] = a10;
  if (row + 1 < M && col + 1 < N) C[(size_t)(row + 1) * N + col + 1] = a11;
}

// block per relation: GRU gates + l2norm, h0 updated in place
__global__ void gru_gate_kernel(const float* __restrict__ gi, const float* __restrict__ gh,
                                const float* __restrict__ b_ih, const float* __restrict__ b_hh,
                                float* __restrict__ h0) {
  int r = blockIdx.x;
  int tid = threadIdx.x;  // 256
  int lane = tid & 63, w = tid >> 6;
  __shared__ float red[4];
  float o = 0.f;
  if (tid < DD) {
    size_t b = (size_t)r * (3 * DD);
    float ir = gi[b + tid] + b_ih[tid];
    float iz = gi[b + DD + tid] + b_ih[DD + tid];
    float inn = gi[b + 2 * DD + tid] + b_ih[2 * DD + tid];
    float hr = gh[b + tid] + b_hh[tid];
    float hz = gh[b + DD + tid] + b_hh[DD + tid];
    float hn = gh[b + 2 * DD + tid] + b_hh[2 * DD + tid];
    float hv = h0[(size_t)r * DD + tid];
    float rr = sigm(ir + hr);
    float z = sigm(iz + hz);
    float n = tanhf(inn + rr * hn);
    o = (1.f - z) * n + z * hv;
  }
  float ss = o * o;
#pragma unroll
  for (int off = 32; off; off >>= 1) ss += __shfl_down(ss, off);
  if (lane == 0) red[w] = ss;
  __syncthreads();
  float tot = red[0] + red[1] + red[2] + red[3];
  float inv = 1.f / fmaxf(sqrtf(tot), 1e-12f);
  if (tid < DD) h0[(size_t)r * DD + tid] = o * inv;
}

// wave per node: agg[n] = norm[n] * sum_{e->n} (hh[src]+h0[et])
__global__ void agg_kernel(const float* __restrict__ hh, const float* __restrict__ h0,
                           const int* __restrict__ rowptr, const int* __restrict__ sorted_edge_t,
                           const int* __restrict__ src_t, const int* __restrict__ et_t,
                           const float* __restrict__ normv_t, float* __restrict__ agg) {
  int w = threadIdx.x >> 6, lane = threadIdx.x & 63;
  int n = blockIdx.x * 4 + w;
  if (n >= NE) return;
  int beg = rowptr[n], end = rowptr[n + 1];
  float a0 = 0, a1 = 0, a2 = 0, a3 = 0;
  for (int i = beg; i < end; i++) {
    int e = sorted_edge_t[i];
    const float* hr = hh + (size_t)src_t[e] * DD;
    const float* qr = h0 + (size_t)et_t[e] * DD;
    a0 += hr[lane] + qr[lane];
    a1 += hr[64 + lane] + qr[64 + lane];
    a2 += hr[128 + lane] + qr[128 + lane];
    if (lane < 8) a3 += hr[192 + lane] + qr[192 + lane];
  }
  float nm = normv_t[n];
  float* out = agg + (size_t)n * DD;
  out[lane] = a0 * nm;
  out[64 + lane] = a1 * nm;
  out[128 + lane] = a2 * nm;
  if (lane < 8) out[192 + lane] = a3 * nm;
}

// C = act(A1@W1 [+ A2@W2]); tile 64 rows x 200 cols; per-thread 8x7 register block
template <int DUAL, int RRELU>
__global__ __launch_bounds__(256) void gemm_kernel(const float* __restrict__ A1,
                                                   const float* __restrict__ W1,
                                                   const float* __restrict__ A2,
                                                   const float* __restrict__ W2,
                                                   float* __restrict__ C) {
  const int KB = 8;
  __shared__ float As[KB][64];
  __shared__ float Ws[KB][DD];
  int tid = threadIdx.x;
  int tx = tid & 31, ty = tid >> 5;
  int row0 = blockIdx.x * 64;
  float acc[8][7];
#pragma unroll
  for (int i = 0; i < 8; i++)
#pragma unroll
    for (int j = 0; j < 7; j++) acc[i][j] = 0.f;

  for (int pass = 0; pass < (DUAL ? 2 : 1); ++pass) {
    const float* A = pass ? A2 : A1;
    const float* W = pass ? W2 : W1;
    for (int k0 = 0; k0 < DD; k0 += KB) {
      __syncthreads();
      {  // stage A: 64 rows x 8 k
        int r = tid >> 2;
        int kk = (tid & 3) * 2;
        int row = row0 + r;
        float v0 = 0.f, v1 = 0.f;
        if (row < NE) {
          v0 = A[(size_t)row * DD + k0 + kk];
          v1 = A[(size_t)row * DD + k0 + kk + 1];
        }
        As[kk][r] = v0;
        As[kk + 1][r] = v1;
      }
      for (int i = tid; i < KB * DD; i += 256) {  // stage W: 8 k x 200 j
        int kk = i / DD, j = i - kk * DD;
        Ws[kk][j] = W[(size_t)(k0 + kk) * DD + j];
      }
      __syncthreads();
#pragma unroll
      for (int kk = 0; kk < KB; ++kk) {
        float a[8];
#pragma unroll
        for (int rr = 0; rr < 8; rr++) a[rr] = As[kk][ty + 8 * rr];
        float b[7];
#pragma unroll
        for (int c = 0; c < 7; c++) {
          int j = tx + 32 * c;
          b[c] = (j < DD) ? Ws[kk][j] : 0.f;
        }
#pragma unroll
        for (int rr = 0; rr < 8; rr++)
#pragma unroll
          for (int c = 0; c < 7; c++) acc[rr][c] += a[rr] * b[c];
      }
    }
  }
#pragma unroll
  for (int rr = 0; rr < 8; rr++) {
    int row = row0 + ty + 8 * rr;
    if (row >= NE) continue;
#pragma unroll
    for (int c = 0; c < 7; c++) {
      int j = tx + 32 * c;
      if (j < DD) {
        float v = acc[rr][c];
        if (RRELU) v = (v >= 0.f) ? v : v * SLOPE;
        C[(size_t)row * DD + j] = v;
      }
    }
  }
}

// wave per node: cur=l2norm(hh); tw=sigmoid(tg+b); h=tw*cur+(1-tw)*h; write hist slice
__global__ void finalize_kernel(const float* __restrict__ hh, const float* __restrict__ tg,
                                const float* __restrict__ tgb, float* __restrict__ h,
                                float* __restrict__ outs) {
  int w = threadIdx.x >> 6, lane = threadIdx.x & 63;
  int n = blockIdx.x * 4 + w;
  if (n >= NE) return;
  size_t base = (size_t)n * DD;
  float c0 = hh[base + lane], c1 = hh[base + 64 + lane], c2 = hh[base + 128 + lane];
  float c3 = (lane < 8) ? hh[base + 192 + lane] : 0.f;
  float ss = c0 * c0 + c1 * c1 + c2 * c2 + c3 * c3;
#pragma unroll
  for (int off = 32; off; off >>= 1) ss += __shfl_down(ss, off);
  ss = __shfl(ss, 0);
  float inv = 1.f / fmaxf(sqrtf(ss), 1e-12f);
  float cv[4] = {c0 * inv, c1 * inv, c2 * inv, c3 * inv};
#pragma unroll
  for (int ch = 0; ch < 4; ch++) {
    int d = ch * 64 + lane;
    if (d < DD) {
      float hv = h[base + d];
      float tw = sigm(tg[base + d] + tgb[d]);
      float nv = tw * cv[ch] + (1.f - tw) * hv;
      h[base + d] = nv;
      outs[base + d] = nv;
    }
  }
}

// ---------- launch ----------

extern "C" void kernel_launch(void* const* d_in, const int* in_sizes, int n_in, void* d_out,
                              int out_size, void* d_ws, size_t ws_size, hipStream_t stream) {
  const int* src = (const int*)d_in[0];
  const int* dst = (const int*)d_in[1];
  const int* et = (const int*)d_in[2];
  const float* dyn = (const float*)d_in[3];
  const float* emb_rel = (const float*)d_in[4];
  const float* W_ih = (const float*)d_in[5];
  const float* W_hh = (const float*)d_in[6];
  const float* b_ih = (const float*)d_in[7];
  const float* b_hh = (const float*)d_in[8];
  const float* W_nb = (const float*)d_in[9];
  const float* W_lp = (const float*)d_in[10];
  const float* Wtg = (const float*)d_in[11];
  const float* tgb = (const float*)d_in[12];
  float* out = (float*)d_out;

  char* p = (char*)d_ws;
  float* h = (float*)p;        p += (size_t)NE * DD * 4;
  float* bufB = (float*)p;     p += (size_t)NE * DD * 4;  // layer-1 out; gi/gh alias here
  float* agg = (float*)p;      p += (size_t)NE * DD * 4;  // also reused for time-gate output
  float* h0 = (float*)p;       p += (size_t)R2C * DD * 4;
  float* X = (float*)p;        p += (size_t)R2C * 400 * 4;  // [emb_rel | xmean]
  float* normv = (float*)p;    p += (size_t)TT * NE * 4;
  int* et_rowptr = (int*)p;    p += (size_t)TT * (R2C + 1) * 4;
  int* et_cursor = (int*)p;    p += (size_t)TT * R2C * 4;
  int* et_hist = (int*)p;      p += (size_t)TT * R2C * 4;
  int* sorted_ent = (int*)p;   p += (size_t)TT * 2 * EE * 4;
  int* dst_rowptr = (int*)p;   p += (size_t)TT * (NE + 1) * 4;
  int* dst_cursor = (int*)p;   p += (size_t)TT * NE * 4;
  int* deg_hist = (int*)p;     p += (size_t)TT * NE * 4;
  int* sorted_edge = (int*)p;  p += (size_t)TT * EE * 4;

  float* gi = bufB;                          // [480, 600] — bufB is dead during GRU phase
  float* gh = bufB + (size_t)R2C * 3 * DD;   // [480, 600]

  hipMemsetAsync(et_hist, 0, (size_t)TT * R2C * 4, stream);
  hipMemsetAsync(deg_hist, 0, (size_t)TT * NE * 4, stream);
  hipMemsetAsync(et_cursor, 0, (size_t)TT * R2C * 4, stream);
  hipMemsetAsync(dst_cursor, 0, (size_t)TT * NE * 4, stream);

  init_h_kernel<<<NE, 64, 0, stream>>>(dyn, h);
  copy_kernel<<<(R2C * DD + 255) / 256, 256, 0, stream>>>(emb_rel, h0, R2C * DD);
  fill_x_kernel<<<(R2C * DD + 255) / 256, 256, 0, stream>>>(emb_rel, X);
  hist_kernel<<<(TT * EE + 255) / 256, 256, 0, stream>>>(et, dst, et_hist, deg_hist);
  scan_rel_kernel<<<TT, 512, 0, stream>>>(et_hist, et_rowptr);
  scan_dst_kernel<<<TT, 1024, 0, stream>>>(deg_hist, dst_rowptr, normv);
  scatter_rel_kernel<<<(TT * EE + 255) / 256, 256, 0, stream>>>(src, dst, et, et_rowptr, et_cursor,
                                                                sorted_ent);
  scatter_dst_kernel<<<(TT * EE + 255) / 256, 256, 0, stream>>>(dst, dst_rowptr, dst_cursor,
                                                                sorted_edge);

  const int gemm_grid = (NE + 63) / 64;
  const dim3 gru_grid((3 * DD + 31) / 32, (R2C + 31) / 32);
  for (int t = 0; t < TT; t++) {
    const int* src_t = src + (size_t)t * EE;
    const int* et_t = et + (size_t)t * EE;
    float* bufA = out + (size_t)t * NE * DD;  // hist slice doubles as layer-0 scratch

    relmean_kernel<<<R2C, 256, 0, stream>>>(h, et_rowptr + t * (R2C + 1),
                                            sorted_ent + (size_t)t * 2 * EE, X);
    // GRU as two small GEMMs + fused gate/l2norm
    gemm_small_bt<<<gru_grid, 256, 0, stream>>>(X, W_ih, gi, R2C, 3 * DD, 2 * DD);
    gemm_small_bt<<<gru_grid, 256, 0, stream>>>(h0, W_hh, gh, R2C, 3 * DD, DD);
    gru_gate_kernel<<<R2C, 256, 0, stream>>>(gi, gh, b_ih, b_hh, h0);
    // layer 0
    agg_kernel<<<(NE + 3) / 4, 256, 0, stream>>>(h, h0, dst_rowptr + t * (NE + 1),
                                                 sorted_edge + (size_t)t * EE, src_t, et_t,
                                                 normv + (size_t)t * NE, agg);
    gemm_kernel<1, 1><<<gemm_grid, 256, 0, stream>>>(agg, W_nb, h, W_lp, bufA);
    // layer 1
    agg_kernel<<<(NE + 3) / 4, 256, 0, stream>>>(bufA, h0, dst_rowptr + t * (NE + 1),
                                                 sorted_edge + (size_t)t * EE, src_t, et_t,
                                                 normv + (size_t)t * NE, agg);
    gemm_kernel<1, 1><<<gemm_grid, 256, 0, stream>>>(agg, W_nb + DD * DD, bufA, W_lp + DD * DD,
                                                     bufB);
    // time gate: tg = h @ Wtg  (reuse agg buffer)
    gemm_kernel<0, 0><<<gemm_grid, 256, 0, stream>>>(h, Wtg, nullptr, nullptr, agg);
    finalize_kernel<<<(NE + 3) / 4, 256, 0, stream>>>(bufB, agg, tgb, h, bufA);
  }
}

// Round 3
// 2170.229 us; speedup vs baseline: 3.0529x; 2.2875x over previous
//
#include <hip/hip_runtime.h>
#include <math.h>

#define NE 50000
#define R2C 480
#define DD 200
#define TT 4
#define EE 100000
#define SLOPE 0.22916666666666666f

typedef short short8 __attribute__((ext_vector_type(8)));
typedef float float4v __attribute__((ext_vector_type(4)));

__device__ __forceinline__ float sigm(float x) { return 1.f / (1.f + expf(-x)); }

__device__ __forceinline__ short f2bf(float f) {  // fp32 -> bf16 RNE
  union { float f; unsigned u; } v;
  v.f = f;
  unsigned r = v.u + 0x7fffu + ((v.u >> 16) & 1u);
  return (short)(r >> 16);
}

// ---------- setup kernels ----------

__global__ void init_h_kernel(const float* __restrict__ emb, float* __restrict__ h) {
  int n = blockIdx.x;            // one 64-lane wave per row
  int lane = threadIdx.x;
  size_t base = (size_t)n * DD;
  float v0 = emb[base + lane];
  float v1 = emb[base + 64 + lane];
  float v2 = emb[base + 128 + lane];
  float v3 = (lane < 8) ? emb[base + 192 + lane] : 0.f;
  float ss = v0 * v0 + v1 * v1 + v2 * v2 + v3 * v3;
#pragma unroll
  for (int off = 32; off; off >>= 1) ss += __shfl_down(ss, off);
  ss = __shfl(ss, 0);
  float inv = 1.f / fmaxf(sqrtf(ss), 1e-12f);
  h[base + lane] = v0 * inv;
  h[base + 64 + lane] = v1 * inv;
  h[base + 128 + lane] = v2 * inv;
  if (lane < 8) h[base + 192 + lane] = v3 * inv;
}

__global__ void copy_kernel(const float* __restrict__ a, float* __restrict__ b, int n) {
  int i = blockIdx.x * blockDim.x + threadIdx.x;
  if (i < n) b[i] = a[i];
}

// X[r][0:200] = emb_rel[r]  (X row stride 400)
__global__ void fill_x_kernel(const float* __restrict__ emb_rel, float* __restrict__ X) {
  int i = blockIdx.x * blockDim.x + threadIdx.x;
  if (i >= R2C * DD) return;
  int r = i / DD, d = i - r * DD;
  X[(size_t)r * 400 + d] = emb_rel[i];
}

__global__ void hist_kernel(const int* __restrict__ et, const int* __restrict__ dst,
                            int* __restrict__ et_hist, int* __restrict__ deg_hist) {
  int i = blockIdx.x * blockDim.x + threadIdx.x;
  if (i >= TT * EE) return;
  int t = i / EE;
  atomicAdd(&et_hist[t * R2C + et[i]], 1);
  atomicAdd(&deg_hist[(size_t)t * NE + dst[i]], 1);
}

__global__ void scan_rel_kernel(const int* __restrict__ et_hist, int* __restrict__ rowptr) {
  int t = blockIdx.x;
  int tid = threadIdx.x;  // block 512
  __shared__ int s[512];
  int v = (tid < R2C) ? 2 * et_hist[t * R2C + tid] : 0;
  s[tid] = v;
  __syncthreads();
  for (int off = 1; off < 512; off <<= 1) {
    int x = (tid >= off) ? s[tid - off] : 0;
    __syncthreads();
    s[tid] += x;
    __syncthreads();
  }
  if (tid < R2C) rowptr[t * (R2C + 1) + tid] = s[tid] - v;
  if (tid == 0) rowptr[t * (R2C + 1) + R2C] = 2 * EE;
}

__global__ void scan_dst_kernel(const int* __restrict__ deg_hist, int* __restrict__ rowptr,
                                float* __restrict__ normv) {
  int t = blockIdx.x;
  int tid = threadIdx.x;  // block 1024
  __shared__ int s[1024];
  __shared__ int carry;
  if (tid == 0) carry = 0;
  __syncthreads();
  for (int base = 0; base < NE; base += 1024) {
    int idx = base + tid;
    int v = (idx < NE) ? deg_hist[(size_t)t * NE + idx] : 0;
    s[tid] = v;
    __syncthreads();
    for (int off = 1; off < 1024; off <<= 1) {
      int x = (tid >= off) ? s[tid - off] : 0;
      __syncthreads();
      s[tid] += x;
      __syncthreads();
    }
    int excl = s[tid] - v + carry;
    if (idx < NE) {
      rowptr[t * (NE + 1) + idx] = excl;
      normv[(size_t)t * NE + idx] = 1.f / fmaxf((float)v, 1.f);
    }
    __syncthreads();
    if (tid == 1023) carry += s[1023];
    __syncthreads();
  }
  if (tid == 0) rowptr[t * (NE + 1) + NE] = EE;
}

__global__ void scatter_rel_kernel(const int* __restrict__ src, const int* __restrict__ dst,
                                   const int* __restrict__ et, const int* __restrict__ rowptr,
                                   int* __restrict__ cursor, int* __restrict__ sorted_ent) {
  int i = blockIdx.x * blockDim.x + threadIdx.x;
  if (i >= TT * EE) return;
  int t = i / EE;
  int r = et[i];
  int base = rowptr[t * (R2C + 1) + r];
  int p1 = base + atomicAdd(&cursor[t * R2C + r], 1);
  sorted_ent[(size_t)t * 2 * EE + p1] = src[i];
  int p2 = base + atomicAdd(&cursor[t * R2C + r], 1);
  sorted_ent[(size_t)t * 2 * EE + p2] = dst[i];
}

__global__ void scatter_dst_kernel(const int* __restrict__ dst, const int* __restrict__ rowptr,
                                   int* __restrict__ cursor, int* __restrict__ sorted_edge) {
  int i = blockIdx.x * blockDim.x + threadIdx.x;
  if (i >= TT * EE) return;
  int t = i / EE, e = i - t * EE;
  int d = dst[i];
  int base = rowptr[t * (NE + 1) + d];
  int p = base + atomicAdd(&cursor[(size_t)t * NE + d], 1);
  sorted_edge[(size_t)t * EE + p] = e;
}

// ---------- per-step kernels ----------

// one block (4 waves) per relation: mean of h rows; writes X[r][200:400] (row stride 400)
__global__ void relmean_kernel(const float* __restrict__ h, const int* __restrict__ rowptr,
                               const int* __restrict__ sorted_ent_t, float* __restrict__ X) {
  int r = blockIdx.x;
  int beg = rowptr[r], end = rowptr[r + 1];
  int lane = threadIdx.x & 63, w = threadIdx.x >> 6;
  float a0 = 0, a1 = 0, a2 = 0, a3 = 0;
  for (int i = beg + w; i < end; i += 4) {
    int idx = sorted_ent_t[i];
    const float* row = h + (size_t)idx * DD;
    a0 += row[lane];
    a1 += row[64 + lane];
    a2 += row[128 + lane];
    if (lane < 8) a3 += row[192 + lane];
  }
  __shared__ float part[4][DD];
  part[w][lane] = a0;
  part[w][64 + lane] = a1;
  part[w][128 + lane] = a2;
  if (lane < 8) part[w][192 + lane] = a3;
  __syncthreads();
  float cnt = fmaxf((float)(end - beg), 1.f);
  for (int d = threadIdx.x; d < DD; d += 256) {
    float s = part[0][d] + part[1][d] + part[2][d] + part[3][d];
    X[(size_t)r * 400 + 200 + d] = s / cnt;
  }
}

// C[M,N] = A[M,K] @ B[N,K]^T  (B row-major [N,K]); tile 32x32, K-chunk 16, 2x2/thread
__global__ __launch_bounds__(256) void gemm_small_bt(const float* __restrict__ A,
                                                     const float* __restrict__ B,
                                                     float* __restrict__ C, int M, int N, int K) {
  __shared__ float As[16][33];
  __shared__ float Bs[16][33];
  int tid = threadIdx.x;
  int col0 = blockIdx.x * 32;
  int row0 = blockIdx.y * 32;
  int tr = tid >> 4, tc = tid & 15;
  float a00 = 0, a01 = 0, a10 = 0, a11 = 0;
  for (int k0 = 0; k0 < K; k0 += 16) {
    __syncthreads();
    for (int i = tid; i < 512; i += 256) {
      int kk = i & 15, r = i >> 4;
      int row = row0 + r, k = k0 + kk;
      As[kk][r] = (row < M && k < K) ? A[(size_t)row * K + k] : 0.f;
    }
    for (int i = tid; i < 512; i += 256) {
      int kk = i & 15, c = i >> 4;
      int col = col0 + c, k = k0 + kk;
      Bs[kk][c] = (col < N && k < K) ? B[(size_t)col * K + k] : 0.f;
    }
    __syncthreads();
#pragma unroll
    for (int kk = 0; kk < 16; kk++) {
      float x0 = As[kk][tr * 2], x1 = As[kk][tr * 2 + 1];
      float y0 = Bs[kk][tc * 2], y1 = Bs[kk][tc * 2 + 1];
      a00 += x0 * y0;
      a01 += x0 * y1;
      a10 += x1 * y0;
      a11 += x1 * y1;
    }
  }
  int row = row0 + tr * 2, col = col0 + tc * 2;
  if (row < M && col < N) C[(size_t)row * N + col] = a00;
  if (row < M && col + 1 < N) C[(size_t)row * N + col + 1] = a01;
  if (row + 1 < M && col < N) C[(size_t)(row + 1) * N + col] = a10;
  if (row + 1 < M && col + 1 < N) C[(size_t)(row + 1) * N + col + 1] = a11;
}

// block per relation: GRU gates + l2norm, h0 updated in place
__global__ void gru_gate_kernel(const float* __restrict__ gi, const float* __restrict__ gh,
                                const float* __restrict__ b_ih, const float* __restrict__ b_hh,
                                float* __restrict__ h0) {
  int r = blockIdx.x;
  int tid = threadIdx.x;  // 256
  int lane = tid & 63, w = tid >> 6;
  __shared__ float red[4];
  float o = 0.f;
  if (tid < DD) {
    size_t b = (size_t)r * (3 * DD);
    float ir = gi[b + tid] + b_ih[tid];
    float iz = gi[b + DD + tid] + b_ih[DD + tid];
    float inn = gi[b + 2 * DD + tid] + b_ih[2 * DD + tid];
    float hr = gh[b + tid] + b_hh[tid];
    float hz = gh[b + DD + tid] + b_hh[DD + tid];
    float hn = gh[b + 2 * DD + tid] + b_hh[2 * DD + tid];
    float hv = h0[(size_t)r * DD + tid];
    float rr = sigm(ir + hr);
    float z = sigm(iz + hz);
    float n = tanhf(inn + rr * hn);
    o = (1.f - z) * n + z * hv;
  }
  float ss = o * o;
#pragma unroll
  for (int off = 32; off; off >>= 1) ss += __shfl_down(ss, off);
  if (lane == 0) red[w] = ss;
  __syncthreads();
  float tot = red[0] + red[1] + red[2] + red[3];
  float inv = 1.f / fmaxf(sqrtf(tot), 1e-12f);
  if (tid < DD) h0[(size_t)r * DD + tid] = o * inv;
}

// wave per node: agg[n] = norm[n] * sum_{e->n} (hh[src]+h0[et])
__global__ void agg_kernel(const float* __restrict__ hh, const float* __restrict__ h0,
                           const int* __restrict__ rowptr, const int* __restrict__ sorted_edge_t,
                           const int* __restrict__ src_t, const int* __restrict__ et_t,
                           const float* __restrict__ normv_t, float* __restrict__ agg) {
  int w = threadIdx.x >> 6, lane = threadIdx.x & 63;
  int n = blockIdx.x * 4 + w;
  if (n >= NE) return;
  int beg = rowptr[n], end = rowptr[n + 1];
  float a0 = 0, a1 = 0, a2 = 0, a3 = 0;
  for (int i = beg; i < end; i++) {
    int e = sorted_edge_t[i];
    const float* hr = hh + (size_t)src_t[e] * DD;
    const float* qr = h0 + (size_t)et_t[e] * DD;
    a0 += hr[lane] + qr[lane];
    a1 += hr[64 + lane] + qr[64 + lane];
    a2 += hr[128 + lane] + qr[128 + lane];
    if (lane < 8) a3 += hr[192 + lane] + qr[192 + lane];
  }
  float nm = normv_t[n];
  float* out = agg + (size_t)n * DD;
  out[lane] = a0 * nm;
  out[64 + lane] = a1 * nm;
  out[128 + lane] = a2 * nm;
  if (lane < 8) out[192 + lane] = a3 * nm;
}

// ---------- MFMA GEMM: C[M,N=200] = act(A1@W1 [+ A2@W2]), bf16 inputs, fp32 acc ----------
// block: 128 rows x 208 cols (200 + pad), 4 waves; wave: 32 rows x 13 col-tiles of 16
// K staged in chunks of 32 as bf16 in LDS; v_mfma_f32_16x16x32_bf16
template <int DUAL, int RRELU>
__global__ __launch_bounds__(256) void gemm_mfma(const float* __restrict__ A1,
                                                 const float* __restrict__ W1,
                                                 const float* __restrict__ A2,
                                                 const float* __restrict__ W2,
                                                 float* __restrict__ C) {
  __shared__ short As[128][40];   // [row][k], rows padded 32->40 shorts (bank spread)
  __shared__ short Bt[208][40];   // [col][k]
  int tid = threadIdx.x;
  int lane = tid & 63, w = tid >> 6;
  int quad = lane >> 4, l16 = lane & 15;
  int row0 = blockIdx.x * 128;

  float4v acc[2][13];
#pragma unroll
  for (int rt = 0; rt < 2; rt++)
#pragma unroll
    for (int ct = 0; ct < 13; ct++) acc[rt][ct] = (float4v){0.f, 0.f, 0.f, 0.f};

  for (int pass = 0; pass < (DUAL ? 2 : 1); ++pass) {
    const float* A = pass ? A2 : A1;
    const float* W = pass ? W2 : W1;
    for (int k0 = 0; k0 < DD; k0 += 32) {
      __syncthreads();
      {  // stage A: 128 rows x 32 k -> bf16
        int r = tid >> 1;
        int kk16 = (tid & 1) * 16;
        int grow = row0 + r;
        short tmp[16];
        const float* ap = A + (size_t)grow * DD;
#pragma unroll
        for (int i = 0; i < 16; i++) {
          int k = k0 + kk16 + i;
          float v = (grow < NE && k < DD) ? ap[k] : 0.f;
          tmp[i] = f2bf(v);
        }
        *(short8*)&As[r][kk16] = *(short8*)&tmp[0];
        *(short8*)&As[r][kk16 + 8] = *(short8*)&tmp[8];
      }
      // stage B transposed: Bt[n][k], 208 cols x 32 k in chunks of 8 k
#pragma unroll
      for (int it = 0; it < 4; it++) {
        int c = tid + it * 256;
        if (c < 832) {
          int n = c % 208;
          int k8 = (c / 208) * 8;
          short tmpb[8];
#pragma unroll
          for (int i = 0; i < 8; i++) {
            int k = k0 + k8 + i;
            float v = (k < DD && n < DD) ? W[(size_t)k * DD + n] : 0.f;
            tmpb[i] = f2bf(v);
          }
          *(short8*)&Bt[n][k8] = *(short8*)&tmpb[0];
        }
      }
      __syncthreads();
      short8 af[2];
#pragma unroll
      for (int rt = 0; rt < 2; rt++)
        af[rt] = *(short8*)&As[w * 32 + rt * 16 + l16][quad * 8];
#pragma unroll
      for (int ct = 0; ct < 13; ct++) {
        short8 bf = *(short8*)&Bt[ct * 16 + l16][quad * 8];
        acc[0][ct] = __builtin_amdgcn_mfma_f32_16x16x32_bf16(af[0], bf, acc[0][ct], 0, 0, 0);
        acc[1][ct] = __builtin_amdgcn_mfma_f32_16x16x32_bf16(af[1], bf, acc[1][ct], 0, 0, 0);
      }
    }
  }
  // epilogue: C[row=quad*4+reg][col=lane&15] per 16x16 tile
#pragma unroll
  for (int rt = 0; rt < 2; rt++) {
#pragma unroll
    for (int ct = 0; ct < 13; ct++) {
      int col = ct * 16 + l16;
      if (col >= DD) continue;
#pragma unroll
      for (int i = 0; i < 4; i++) {
        int row = row0 + w * 32 + rt * 16 + quad * 4 + i;
        if (row < NE) {
          float v = acc[rt][ct][i];
          if (RRELU) v = (v >= 0.f) ? v : v * SLOPE;
          C[(size_t)row * DD + col] = v;
        }
      }
    }
  }
}

// wave per node: cur=l2norm(hh); tw=sigmoid(tg+b); h=tw*cur+(1-tw)*h; write hist slice
__global__ void finalize_kernel(const float* __restrict__ hh, const float* __restrict__ tg,
                                const float* __restrict__ tgb, float* __restrict__ h,
                                float* __restrict__ outs) {
  int w = threadIdx.x >> 6, lane = threadIdx.x & 63;
  int n = blockIdx.x * 4 + w;
  if (n >= NE) return;
  size_t base = (size_t)n * DD;
  float c0 = hh[base + lane], c1 = hh[base + 64 + lane], c2 = hh[base + 128 + lane];
  float c3 = (lane < 8) ? hh[base + 192 + lane] : 0.f;
  float ss = c0 * c0 + c1 * c1 + c2 * c2 + c3 * c3;
#pragma unroll
  for (int off = 32; off; off >>= 1) ss += __shfl_down(ss, off);
  ss = __shfl(ss, 0);
  float inv = 1.f / fmaxf(sqrtf(ss), 1e-12f);
  float cv[4] = {c0 * inv, c1 * inv, c2 * inv, c3 * inv};
#pragma unroll
  for (int ch = 0; ch < 4; ch++) {
    int d = ch * 64 + lane;
    if (d < DD) {
      float hv = h[base + d];
      float tw = sigm(tg[base + d] + tgb[d]);
      float nv = tw * cv[ch] + (1.f - tw) * hv;
      h[base + d] = nv;
      outs[base + d] = nv;
    }
  }
}

// ---------- launch ----------

extern "C" void kernel_launch(void* const* d_in, const int* in_sizes, int n_in, void* d_out,
                              int out_size, void* d_ws, size_t ws_size, hipStream_t stream) {
  const int* src = (const int*)d_in[0];
  const int* dst = (const int*)d_in[1];
  const int* et = (const int*)d_in[2];
  const float* dyn = (const float*)d_in[3];
  const float* emb_rel = (const float*)d_in[4];
  const float* W_ih = (const float*)d_in[5];
  const float* W_hh = (const float*)d_in[6];
  const float* b_ih = (const float*)d_in[7];
  const float* b_hh = (const float*)d_in[8];
  const float* W_nb = (const float*)d_in[9];
  const float* W_lp = (const float*)d_in[10];
  const float* Wtg = (const float*)d_in[11];
  const float* tgb = (const float*)d_in[12];
  float* out = (float*)d_out;

  char* p = (char*)d_ws;
  float* h = (float*)p;        p += (size_t)NE * DD * 4;
  float* bufB = (float*)p;     p += (size_t)NE * DD * 4;  // layer-1 out; gi/gh alias here
  float* agg = (float*)p;      p += (size_t)NE * DD * 4;  // also reused for time-gate output
  float* h0 = (float*)p;       p += (size_t)R2C * DD * 4;
  float* X = (float*)p;        p += (size_t)R2C * 400 * 4;  // [emb_rel | xmean]
  float* normv = (float*)p;    p += (size_t)TT * NE * 4;
  int* et_rowptr = (int*)p;    p += (size_t)TT * (R2C + 1) * 4;
  int* et_cursor = (int*)p;    p += (size_t)TT * R2C * 4;
  int* et_hist = (int*)p;      p += (size_t)TT * R2C * 4;
  int* sorted_ent = (int*)p;   p += (size_t)TT * 2 * EE * 4;
  int* dst_rowptr = (int*)p;   p += (size_t)TT * (NE + 1) * 4;
  int* dst_cursor = (int*)p;   p += (size_t)TT * NE * 4;
  int* deg_hist = (int*)p;     p += (size_t)TT * NE * 4;
  int* sorted_edge = (int*)p;  p += (size_t)TT * EE * 4;

  float* gi = bufB;                          // [480, 600] — bufB is dead during GRU phase
  float* gh = bufB + (size_t)R2C * 3 * DD;   // [480, 600]

  hipMemsetAsync(et_hist, 0, (size_t)TT * R2C * 4, stream);
  hipMemsetAsync(deg_hist, 0, (size_t)TT * NE * 4, stream);
  hipMemsetAsync(et_cursor, 0, (size_t)TT * R2C * 4, stream);
  hipMemsetAsync(dst_cursor, 0, (size_t)TT * NE * 4, stream);

  init_h_kernel<<<NE, 64, 0, stream>>>(dyn, h);
  copy_kernel<<<(R2C * DD + 255) / 256, 256, 0, stream>>>(emb_rel, h0, R2C * DD);
  fill_x_kernel<<<(R2C * DD + 255) / 256, 256, 0, stream>>>(emb_rel, X);
  hist_kernel<<<(TT * EE + 255) / 256, 256, 0, stream>>>(et, dst, et_hist, deg_hist);
  scan_rel_kernel<<<TT, 512, 0, stream>>>(et_hist, et_rowptr);
  scan_dst_kernel<<<TT, 1024, 0, stream>>>(deg_hist, dst_rowptr, normv);
  scatter_rel_kernel<<<(TT * EE + 255) / 256, 256, 0, stream>>>(src, dst, et, et_rowptr, et_cursor,
                                                                sorted_ent);
  scatter_dst_kernel<<<(TT * EE + 255) / 256, 256, 0, stream>>>(dst, dst_rowptr, dst_cursor,
                                                                sorted_edge);

  const int gemm_grid = (NE + 127) / 128;
  const dim3 gru_grid((3 * DD + 31) / 32, (R2C + 31) / 32);
  for (int t = 0; t < TT; t++) {
    const int* src_t = src + (size_t)t * EE;
    const int* et_t = et + (size_t)t * EE;
    float* bufA = out + (size_t)t * NE * DD;  // hist slice doubles as layer-0 scratch

    relmean_kernel<<<R2C, 256, 0, stream>>>(h, et_rowptr + t * (R2C + 1),
                                            sorted_ent + (size_t)t * 2 * EE, X);
    // GRU as two small GEMMs + fused gate/l2norm
    gemm_small_bt<<<gru_grid, 256, 0, stream>>>(X, W_ih, gi, R2C, 3 * DD, 2 * DD);
    gemm_small_bt<<<gru_grid, 256, 0, stream>>>(h0, W_hh, gh, R2C, 3 * DD, DD);
    gru_gate_kernel<<<R2C, 256, 0, stream>>>(gi, gh, b_ih, b_hh, h0);
    // layer 0
    agg_kernel<<<(NE + 3) / 4, 256, 0, stream>>>(h, h0, dst_rowptr + t * (NE + 1),
                                                 sorted_edge + (size_t)t * EE, src_t, et_t,
                                                 normv + (size_t)t * NE, agg);
    gemm_mfma<1, 1><<<gemm_grid, 256, 0, stream>>>(agg, W_nb, h, W_lp, bufA);
    // layer 1
    agg_kernel<<<(NE + 3) / 4, 256, 0, stream>>>(bufA, h0, dst_rowptr + t * (NE + 1),
                                                 sorted_edge + (size_t)t * EE, src_t, et_t,
                                                 normv + (size_t)t * NE, agg);
    gemm_mfma<1, 1><<<gemm_grid, 256, 0, stream>>>(agg, W_nb + DD * DD, bufA, W_lp + DD * DD,
                                                   bufB);
    // time gate: tg = h @ Wtg  (reuse agg buffer)
    gemm_mfma<0, 0><<<gemm_grid, 256, 0, stream>>>(h, Wtg, nullptr, nullptr, agg);
    finalize_kernel<<<(NE + 3) / 4, 256, 0, stream>>>(bufB, agg, tgb, h, bufA);
  }
}